// Round 6
// baseline (2682.476 us; speedup 1.0000x reference)
//
#include <hip/hip_runtime.h>
#include <cstdint>
#include <cstddef>

static constexpr int NPTS  = 4096;
static constexpr int NB    = 8;
static constexpr int NROWS = NB * NPTS;      // 32768
static constexpr int KNN   = 32;

typedef __attribute__((ext_vector_type(8))) short  bf16x8;
typedef __attribute__((ext_vector_type(4))) float  f32x4;

// ---------------- utility: 64-bit shuffles built from 32-bit ----------------
__device__ __forceinline__ unsigned long long shfl_xor_u64(unsigned long long v, int m) {
  int lo = __shfl_xor((int)(unsigned)(v & 0xFFFFFFFFULL), m, 64);
  int hi = __shfl_xor((int)(unsigned)(v >> 32), m, 64);
  return ((unsigned long long)(unsigned)hi << 32) | (unsigned)lo;
}
__device__ __forceinline__ unsigned long long shfl_u64(unsigned long long v, int src) {
  int lo = __shfl((int)(unsigned)(v & 0xFFFFFFFFULL), src, 64);
  int hi = __shfl((int)(unsigned)(v >> 32), src, 64);
  return ((unsigned long long)(unsigned)hi << 32) | (unsigned)lo;
}

// ---------------- squared norms per point ----------------
__global__ __launch_bounds__(256) void sqnorm_kernel(const float* __restrict__ x,
                                                     float* __restrict__ sq, int F) {
  int t = blockIdx.x * 256 + threadIdx.x;
  if (t >= NROWS) return;
  const float* p = x + (size_t)t * F;
  float s = 0.f;
  for (int f = 0; f < F; ++f) s = fmaf(p[f], p[f], s);
  sq[t] = s;
}

// ---------------- split fp32 -> bf16 hi + bf16 lo (RNE) ----------------
__global__ __launch_bounds__(256) void split_kernel(const float* __restrict__ x,
                                                    unsigned short* __restrict__ hi,
                                                    unsigned short* __restrict__ lo,
                                                    int total) {
  int t = blockIdx.x * 256 + threadIdx.x;
  if (t >= total) return;
  float v = x[t];
  unsigned u = __float_as_uint(v);
  unsigned h = (u + 0x7FFFu + ((u >> 16) & 1u)) >> 16;
  float hf = __uint_as_float(h << 16);
  float r = v - hf;
  unsigned ur = __float_as_uint(r);
  unsigned l = (ur + 0x7FFFu + ((ur >> 16) & 1u)) >> 16;
  hi[t] = (unsigned short)h;
  lo[t] = (unsigned short)l;
}

// ---------------- per-batch max of sq ----------------
__global__ __launch_bounds__(256) void batchmax_kernel(const float* __restrict__ sq,
                                                       float* __restrict__ sqmax) {
  int b = blockIdx.x, t = threadIdx.x;
  float m = 0.f;
  for (int i = t; i < NPTS; i += 256) m = fmaxf(m, sq[b * NPTS + i]);
  for (int off = 32; off >= 1; off >>= 1) m = fmaxf(m, __shfl_xor(m, off, 64));
  __shared__ float ls[4];
  if ((t & 63) == 0) ls[t >> 6] = m;
  __syncthreads();
  if (t == 0) sqmax[b] = fmaxf(fmaxf(ls[0], ls[1]), fmaxf(ls[2], ls[3]));
}

// =====================================================================
// MFMA kNN (F=64): certified approx screen + exact fp32 rerank.
// Block = 256 thr (4 waves), 16 query rows, grid = 8 batches x 256.
// Sweep1: D_approx via 3-term bf16 MFMA (hh+hl+lh); per-(lane,row) top-2
//   over the lane's 64 cols -> tau[row] = min over waves of (max over 16
//   lanes of 2nd-min)  => >=32 distinct cands <= tau (approx domain).
// |d_approx - d_exact| <= eps = 6e-5*(sq_i+sqmax)+1e-5  (>=2x margin over
//   the 4*2^-18*sqrt(sq_i*sq_j) + fp32-accum bound).  Screen d_a <= tau+2eps
//   provably admits every exact-(dist,idx) top-32 member.
// Sweep2: recompute (cheap), append survivors to per-row LDS lists.
// Rerank: exact fp32 ascending-ch fma chain (bit-identical to R3/R4/R5)
//   + validated lex-(dist,idx) ballot-insert  => output sets identical.
// =====================================================================
__global__ __launch_bounds__(256, 2)
void knn_mfma(const unsigned short* __restrict__ hi,
              const unsigned short* __restrict__ lo,
              const float* __restrict__ x, const float* __restrict__ sq,
              const float* __restrict__ sqmax, int* __restrict__ idx_out) {
  constexpr int CAP = 512;
  constexpr int FP  = 72;     // padded LDS row stride (bf16 elems), 144 B = 9*16
  __shared__ __attribute__((aligned(16))) unsigned short chi[128 * FP];
  __shared__ __attribute__((aligned(16))) unsigned short clo[128 * FP];
  __shared__ float csq[128];
  __shared__ __attribute__((aligned(16))) float xis[16 * 64];
  __shared__ float tauw[4][16];
  __shared__ float tinf_s[16];
  __shared__ int   cnt_s[16];
  __shared__ int   list_s[16 * CAP];

  const int t = threadIdx.x, wave = t >> 6, lane = t & 63;
  const int l16 = lane & 15, quad = lane >> 4;
  const int bid = blockIdx.x;
  const int b   = bid & 7;            // batch pinned by XCD heuristic
  const int i0  = (bid >> 3) << 4;    // 16 rows per block
  const size_t base = (size_t)b * NPTS;
  const unsigned short* hib = hi + base * 64;
  const unsigned short* lob = lo + base * 64;
  const float* sqb = sq + base;
  const float* xb  = x + base * 64;

  // ---- A-fragments (16 query rows, hi/lo, two K=32 halves) ----
  bf16x8 ahi[2], alo[2];
#pragma unroll
  for (int kb = 0; kb < 2; ++kb) {
    ahi[kb] = *(const bf16x8*)(hib + (size_t)(i0 + l16) * 64 + kb * 32 + quad * 8);
    alo[kb] = *(const bf16x8*)(lob + (size_t)(i0 + l16) * 64 + kb * 32 + quad * 8);
  }
  float sqi4[4];
#pragma unroll
  for (int r = 0; r < 4; ++r) sqi4[r] = sqb[i0 + quad * 4 + r];

  // stage fp32 queries for the rerank
  { int r = t >> 4, c4 = t & 15;
    *(float4*)&xis[r * 64 + c4 * 4] =
        *(const float4*)(xb + (size_t)(i0 + r) * 64 + c4 * 4); }
  if (t < 16) cnt_s[t] = 0;

  float t1[4], t2[4];
#pragma unroll
  for (int r = 0; r < 4; ++r) { t1[r] = 3.4e38f; t2[r] = 3.4e38f; }
  float tinf4[4] = {0.f, 0.f, 0.f, 0.f};

  for (int pass = 0; pass < 2; ++pass) {
    for (int tile = 0; tile < 32; ++tile) {
      __syncthreads();
      // ---- stage 128 candidates (hi/lo, padded) ----
#pragma unroll
      for (int p = 0; p < 4; ++p) {
        int slot = t + p * 256;             // 0..1023
        int r = slot >> 3, c8 = slot & 7;
        *(bf16x8*)&chi[r * FP + c8 * 8] =
            *(const bf16x8*)(hib + (size_t)(tile * 128 + r) * 64 + c8 * 8);
        *(bf16x8*)&clo[r * FP + c8 * 8] =
            *(const bf16x8*)(lob + (size_t)(tile * 128 + r) * 64 + c8 * 8);
      }
      if (t < 128) csq[t] = sqb[tile * 128 + t];
      __syncthreads();

#pragma unroll
      for (int sub = 0; sub < 2; ++sub) {
        const int jl = wave * 32 + sub * 16 + l16;   // local candidate row
        bf16x8 bhi0 = *(const bf16x8*)&chi[jl * FP + 0 * 32 + quad * 8];
        bf16x8 bhi1 = *(const bf16x8*)&chi[jl * FP + 1 * 32 + quad * 8];
        bf16x8 blo0 = *(const bf16x8*)&clo[jl * FP + 0 * 32 + quad * 8];
        bf16x8 blo1 = *(const bf16x8*)&clo[jl * FP + 1 * 32 + quad * 8];
        f32x4 acc = {0.f, 0.f, 0.f, 0.f};
        acc = __builtin_amdgcn_mfma_f32_16x16x32_bf16(ahi[0], bhi0, acc, 0, 0, 0);
        acc = __builtin_amdgcn_mfma_f32_16x16x32_bf16(ahi[1], bhi1, acc, 0, 0, 0);
        acc = __builtin_amdgcn_mfma_f32_16x16x32_bf16(ahi[0], blo0, acc, 0, 0, 0);
        acc = __builtin_amdgcn_mfma_f32_16x16x32_bf16(ahi[1], blo1, acc, 0, 0, 0);
        acc = __builtin_amdgcn_mfma_f32_16x16x32_bf16(alo[0], bhi0, acc, 0, 0, 0);
        acc = __builtin_amdgcn_mfma_f32_16x16x32_bf16(alo[1], bhi1, acc, 0, 0, 0);
        const float cs = csq[jl];
        const int jglob = tile * 128 + jl;
#pragma unroll
        for (int r = 0; r < 4; ++r) {       // C/D: col=l16, row=quad*4+r
          float d = fmaf(-2.f, acc[r], sqi4[r] + cs);
          if (pass == 0) {
            float lo_ = fminf(d, t1[r]);
            float hi_ = fmaxf(d, t1[r]);
            t1[r] = lo_;
            t2[r] = fminf(t2[r], hi_);
          } else {
            if (d <= tinf4[r]) {
              int pos = atomicAdd(&cnt_s[quad * 4 + r], 1);
              if (pos < CAP) list_s[(quad * 4 + r) * CAP + pos] = jglob;
            }
          }
        }
      }
    }
    if (pass == 0) {
      // per-wave bound: max over the quad's 16 lanes of 2nd-min
      float v[4];
#pragma unroll
      for (int r = 0; r < 4; ++r) {
        v[r] = t2[r];
#pragma unroll
        for (int off = 1; off < 16; off <<= 1)
          v[r] = fmaxf(v[r], __shfl_xor(v[r], off, 64));
      }
      if (l16 == 0)
#pragma unroll
        for (int r = 0; r < 4; ++r) tauw[wave][quad * 4 + r] = v[r];
      __syncthreads();
      if (t < 16) {
        float tf = fminf(fminf(tauw[0][t], tauw[1][t]), fminf(tauw[2][t], tauw[3][t]));
        float si = sqb[i0 + t];
        float eps = 6e-5f * (si + sqmax[b]) + 1e-5f;
        tinf_s[t] = tf + 2.f * eps;
      }
      __syncthreads();
#pragma unroll
      for (int r = 0; r < 4; ++r) tinf4[r] = tinf_s[quad * 4 + r];
    }
  }
  __syncthreads();

  // -------- exact fp32 rerank of survivors (4 rows per wave) --------
  for (int rr = 0; rr < 4; ++rr) {
    const int r = wave * 4 + rr;
    const int n0 = cnt_s[r];
    const int n = n0 < CAP ? n0 : CAP;
    const float sqi = sqb[i0 + r];
    const float4* xirow = (const float4*)&xis[r * 64];
    unsigned long long ent = (0xFFFFFFFFFFFULL << 5) | (unsigned long long)(lane & 31);
    unsigned long long M   = (0xFFFFFFFFFFFULL << 5) | 31ULL;
    for (int c0 = 0; c0 < n; c0 += 64) {
      const int li = c0 + lane;
      unsigned long long cq = 0xFFFFFFFFFFFULL;
      if (li < n) {
        const int j = list_s[r * CAP + li];
        const float4* xj = (const float4*)(xb + (size_t)j * 64);
        float dot = 0.f;
#pragma unroll
        for (int c4 = 0; c4 < 16; ++c4) {
          float4 q = xirow[c4];
          float4 c = xj[c4];
          dot = fmaf(q.x, c.x, dot);
          dot = fmaf(q.y, c.y, dot);
          dot = fmaf(q.z, c.z, dot);
          dot = fmaf(q.w, c.w, dot);
        }
        float d = fmaf(-2.f, dot, sqi + sqb[j]);
        unsigned u  = __float_as_uint(d);
        unsigned ck = (u & 0x80000000u) ? ~u : (u | 0x80000000u);
        cq = ((unsigned long long)ck << 12) | (unsigned)j;
      }
      unsigned long long mask = __ballot(cq < (M >> 5));
      while (mask) {
        const int src = __builtin_ctzll(mask);
        mask &= mask - 1;
        const unsigned long long bq = shfl_u64(cq, src);
        if (bq < (M >> 5)) {
          const unsigned slot = (unsigned)(M & 31ULL);
          if ((unsigned)(lane & 31) == slot) ent = (bq << 5) | slot;
          unsigned long long v = ent;
#pragma unroll
          for (int off = 16; off >= 1; off >>= 1) {
            unsigned long long w2 = shfl_xor_u64(v, off);
            v = (v > w2) ? v : w2;
          }
          M = v;
        }
      }
    }
    if (lane < 32)
      idx_out[(size_t)(base + i0 + r) * 32 + lane] =
          (int)base + (int)((ent >> 5) & 0xFFFULL);
  }
}

// ---------------- F=3 kNN (validated two-pass VALU path) ----------------
template <int F>
__global__ __launch_bounds__(256, 2) void knn_tiled(const float* __restrict__ x,
                                                    const float* __restrict__ sq,
                                                    int* __restrict__ idx_out) {
  constexpr int FP = 4;
  constexpr int TC = 256;
  constexpr int RPB = 32;
  constexpr int RPW = 8;

  __shared__ __attribute__((aligned(16))) float qv[RPB][FP];
  __shared__ float qsq[RPB];
  __shared__ __attribute__((aligned(16))) float ct[TC][FP];
  __shared__ float csq[TC];

  const int t    = threadIdx.x;
  const int wave = t >> 6;
  const int lane = t & 63;
  const int rowbase = blockIdx.x << 5;
  const int b     = rowbase >> 12;
  const int ibase = rowbase & (NPTS - 1);
  const float* xb  = x + (size_t)b * NPTS * F;
  const float* sqb = sq + (b << 12);

  if (t < RPB) {
    qv[t][0] = xb[(size_t)(ibase + t) * 3 + 0];
    qv[t][1] = xb[(size_t)(ibase + t) * 3 + 1];
    qv[t][2] = xb[(size_t)(ibase + t) * 3 + 2];
    qv[t][3] = 0.f;
    qsq[t] = sqb[ibase + t];
  }
  __syncthreads();

  const int r0 = wave << 3;
  float sqi[RPW];
#pragma unroll
  for (int rr = 0; rr < RPW; ++rr) sqi[rr] = qsq[r0 + rr];

  unsigned mn[RPW];
#pragma unroll
  for (int rr = 0; rr < RPW; ++rr) mn[rr] = 0xFFFFFFFFu;

  for (int tile = 0; tile < NPTS / TC; ++tile) {
    __syncthreads();
    {
      int jg = tile * TC + t;
      ct[t][0] = xb[(size_t)jg * 3 + 0];
      ct[t][1] = xb[(size_t)jg * 3 + 1];
      ct[t][2] = xb[(size_t)jg * 3 + 2];
      ct[t][3] = 0.f;
      csq[t] = sqb[jg];
    }
    __syncthreads();

    float4 c0 = *reinterpret_cast<const float4*>(&ct[lane][0]);
    float4 c1 = *reinterpret_cast<const float4*>(&ct[lane + 64][0]);
    float4 c2 = *reinterpret_cast<const float4*>(&ct[lane + 128][0]);
    float4 c3 = *reinterpret_cast<const float4*>(&ct[lane + 192][0]);
    float cs[4];
#pragma unroll
    for (int s = 0; s < 4; ++s) cs[s] = csq[lane + 64 * s];

#pragma unroll
    for (int rr = 0; rr < RPW; ++rr) {
      float4 q = *reinterpret_cast<const float4*>(&qv[r0 + rr][0]);
      float dd[4];
      dd[0] = fmaf(q.z, c0.z, fmaf(q.y, c0.y, q.x * c0.x));
      dd[1] = fmaf(q.z, c1.z, fmaf(q.y, c1.y, q.x * c1.x));
      dd[2] = fmaf(q.z, c2.z, fmaf(q.y, c2.y, q.x * c2.x));
      dd[3] = fmaf(q.z, c3.z, fmaf(q.y, c3.y, q.x * c3.x));
#pragma unroll
      for (int s = 0; s < 4; ++s) {
        float d = fmaf(-2.f, dd[s], sqi[rr] + cs[s]);
        unsigned u  = __float_as_uint(d);
        unsigned ck = (u & 0x80000000u) ? ~u : (u | 0x80000000u);
        mn[rr] = ck < mn[rr] ? ck : mn[rr];
      }
    }
  }

  unsigned tau[RPW];
#pragma unroll
  for (int rr = 0; rr < RPW; ++rr) {
    const unsigned v = mn[rr];
    unsigned prefix = 0;
    int need = 32;
    int act = 1;
    for (int bit = 31; bit >= 0; --bit) {
      const unsigned bv = (v >> bit) & 1u;
      unsigned long long m0 = __ballot(act && (bv == 0u));
      int c0n = (int)__popcll(m0);
      if (c0n >= need) {
        act = act && (bv == 0u);
      } else {
        need -= c0n;
        act = act && (bv == 1u);
        prefix |= (1u << bit);
      }
    }
    tau[rr] = prefix;
  }

  unsigned long long ent[RPW], M[RPW];
#pragma unroll
  for (int rr = 0; rr < RPW; ++rr) {
    ent[rr] = (0xFFFFFFFFFFFULL << 5) | (unsigned long long)(lane & 31);
    M[rr]   = (0xFFFFFFFFFFFULL << 5) | 31ULL;
  }

  for (int tile = 0; tile < NPTS / TC; ++tile) {
    __syncthreads();
    {
      int jg = tile * TC + t;
      ct[t][0] = xb[(size_t)jg * 3 + 0];
      ct[t][1] = xb[(size_t)jg * 3 + 1];
      ct[t][2] = xb[(size_t)jg * 3 + 2];
      ct[t][3] = 0.f;
      csq[t] = sqb[jg];
    }
    __syncthreads();

    float4 c0 = *reinterpret_cast<const float4*>(&ct[lane][0]);
    float4 c1 = *reinterpret_cast<const float4*>(&ct[lane + 64][0]);
    float4 c2 = *reinterpret_cast<const float4*>(&ct[lane + 128][0]);
    float4 c3 = *reinterpret_cast<const float4*>(&ct[lane + 192][0]);
    float cs[4];
#pragma unroll
    for (int s = 0; s < 4; ++s) cs[s] = csq[lane + 64 * s];

#pragma unroll
    for (int rr = 0; rr < RPW; ++rr) {
      float4 q = *reinterpret_cast<const float4*>(&qv[r0 + rr][0]);
      float dd[4];
      dd[0] = fmaf(q.z, c0.z, fmaf(q.y, c0.y, q.x * c0.x));
      dd[1] = fmaf(q.z, c1.z, fmaf(q.y, c1.y, q.x * c1.x));
      dd[2] = fmaf(q.z, c2.z, fmaf(q.y, c2.y, q.x * c2.x));
      dd[3] = fmaf(q.z, c3.z, fmaf(q.y, c3.y, q.x * c3.x));
#pragma unroll
      for (int s = 0; s < 4; ++s) {
        float d = fmaf(-2.f, dd[s], sqi[rr] + cs[s]);
        unsigned u  = __float_as_uint(d);
        unsigned ck = (u & 0x80000000u) ? ~u : (u | 0x80000000u);
        unsigned long long mask = __ballot(ck <= tau[rr]);
        while (mask) {
          const int src = __builtin_ctzll(mask);
          mask &= mask - 1;
          const unsigned bk   = (unsigned)__shfl((int)ck, src, 64);
          const unsigned bidx = (unsigned)(tile * TC + s * 64 + src);
          const unsigned long long bq = ((unsigned long long)bk << 12) | bidx;
          if (bq < (M[rr] >> 5)) {
            const unsigned slot = (unsigned)(M[rr] & 31ULL);
            if ((unsigned)(lane & 31) == slot)
              ent[rr] = (bq << 5) | slot;
            unsigned long long v = ent[rr];
#pragma unroll
            for (int off = 16; off >= 1; off >>= 1) {
              unsigned long long w2 = shfl_xor_u64(v, off);
              v = (v > w2) ? v : w2;
            }
            M[rr] = v;
          }
        }
      }
    }
  }

  if (lane < 32) {
#pragma unroll
    for (int rr = 0; rr < RPW; ++rr)
      idx_out[((rowbase + r0 + rr) << 5) + lane] =
          (b << 12) + (int)((ent[rr] >> 5) & 0xFFFULL);
  }
}

// ---------------- per-node P = x.Wbot ; C = x.(Wtop-Wbot) + b ----------------
__global__ __launch_bounds__(256) void mlp_pc_kernel(const float* __restrict__ xin,
                                                     const float* __restrict__ W,
                                                     const float* __restrict__ bias,
                                                     float* __restrict__ P,
                                                     float* C,
                                                     int F, int O, int total) {
  int t = blockIdx.x * 256 + threadIdx.x;
  if (t >= total) return;
  int n = t / O, o = t % O;
  const float* xr = xin + (size_t)n * F;
  const float* Wt = W + o;
  const float* Wb = W + (size_t)F * O + o;
  float p = 0.f, c = 0.f;
  for (int f = 0; f < F; ++f) {
    float a  = xr[f];
    float wt = Wt[(size_t)f * O];
    float wb = Wb[(size_t)f * O];
    p = fmaf(a, wb, p);
    c = fmaf(a, wt - wb, c);
  }
  P[t] = p;
  C[t] = c + bias[o];
}

// ---------------- h[t] (pre-filled with C) += max_k P[idx_k] ----------------
__global__ __launch_bounds__(256) void aggregate_kernel(const int* __restrict__ idx,
                                                        const float* __restrict__ P,
                                                        float* h, int O, int total) {
  int t = blockIdx.x * 256 + threadIdx.x;
  if (t >= total) return;
  int n = t / O, o = t % O;
  const int* ix = idx + (size_t)n * KNN;
  float m = -3.402823466e+38f;
  for (int k = 0; k < KNN; ++k) {
    int jg = ix[k];
    float v = P[(size_t)jg * O + o];
    m = fmaxf(m, v);
  }
  h[t] = h[t] + m;
}

// ---------------- BN stats over relu(h): mean + invstd per channel ----------
__global__ __launch_bounds__(256) void bn_stats_kernel(const float* __restrict__ h,
                                                       float* __restrict__ stats) {
  const int c = blockIdx.x;
  const int t = threadIdx.x;
  double s = 0.0, s2 = 0.0;
  for (int n = t; n < NROWS; n += 256) {
    float v = h[(size_t)n * 64 + c];
    v = v > 0.f ? v : 0.f;
    s += v;
    s2 += (double)v * v;
  }
  __shared__ double ls[256], ls2[256];
  ls[t] = s; ls2[t] = s2;
  __syncthreads();
  for (int st = 128; st; st >>= 1) {
    if (t < st) { ls[t] += ls[t + st]; ls2[t] += ls2[t + st]; }
    __syncthreads();
  }
  if (t == 0) {
    double mean = ls[0] / (double)NROWS;
    double var  = ls2[0] / (double)NROWS - mean * mean;
    stats[c]      = (float)mean;
    stats[64 + c] = (float)(1.0 / sqrt(var + 1e-5));
  }
}

// ---------------- apply: out = (relu(h)-mean)*invstd*g + be ----------------
__global__ __launch_bounds__(256) void bn_apply_kernel(const float* h,
                                                       const float* __restrict__ stats,
                                                       const float* __restrict__ g,
                                                       const float* __restrict__ be,
                                                       float* out, int total) {
  int t = blockIdx.x * 256 + threadIdx.x;
  if (t >= total) return;
  int ch = t & 63;
  float v = fmaxf(h[t], 0.f);
  out[t] = (v - stats[ch]) * stats[64 + ch] * g[ch] + be[ch];
}

// ---------------- write h3 to out + per-block loss partials ----------------
__global__ __launch_bounds__(256) void final_kernel(const float* __restrict__ h3,
                                                    const float* __restrict__ target,
                                                    float* __restrict__ out,
                                                    double* __restrict__ partial) {
  double s = 0.0;
  for (int t = blockIdx.x * 256 + threadIdx.x; t < NROWS * 3; t += 256 * 256) {
    float v = h3[t];
    out[t] = v;
    float d = v - target[t];
    s += (double)d * d;
  }
  __shared__ double ls[256];
  int t = threadIdx.x;
  ls[t] = s;
  __syncthreads();
  for (int st = 128; st; st >>= 1) {
    if (t < st) ls[t] += ls[t + st];
    __syncthreads();
  }
  if (t == 0) partial[blockIdx.x] = ls[0];
}

__global__ __launch_bounds__(256) void loss_kernel(const double* __restrict__ partial,
                                                   float* __restrict__ out) {
  int t = threadIdx.x;
  __shared__ double ls[256];
  ls[t] = partial[t];
  __syncthreads();
  for (int st = 128; st; st >>= 1) {
    if (t < st) ls[t] += ls[t + st];
    __syncthreads();
  }
  if (t == 0) out[NROWS * 3] = (float)(ls[0] / (double)(NROWS * 3));
}

// ---------------- driver ----------------
extern "C" void kernel_launch(void* const* d_in, const int* in_sizes, int n_in,
                              void* d_out, int out_size, void* d_ws, size_t ws_size,
                              hipStream_t stream) {
  const float* x   = (const float*)d_in[0];
  const float* tgt = (const float*)d_in[1];
  const float* W1  = (const float*)d_in[2];
  const float* b1  = (const float*)d_in[3];
  const float* g1  = (const float*)d_in[4];
  const float* be1 = (const float*)d_in[5];
  const float* W2  = (const float*)d_in[6];
  const float* b2  = (const float*)d_in[7];
  const float* g2  = (const float*)d_in[8];
  const float* be2 = (const float*)d_in[9];
  const float* W3  = (const float*)d_in[10];
  const float* b3  = (const float*)d_in[11];
  float* out = (float*)d_out;

  char* ws = (char*)d_ws;
  size_t off = 0;
  float* sq    = (float*)(ws + off); off += (size_t)NROWS * 4;
  int*   idxb  = (int*)(ws + off);   off += (size_t)NROWS * KNN * 4;
  float* P     = (float*)(ws + off); off += (size_t)NROWS * 64 * 4;
  float* CA    = (float*)(ws + off); off += (size_t)NROWS * 64 * 4;
  float* CB    = (float*)(ws + off); off += (size_t)NROWS * 64 * 4;
  unsigned short* hib = (unsigned short*)(ws + off); off += (size_t)NROWS * 64 * 2;
  unsigned short* lob = (unsigned short*)(ws + off); off += (size_t)NROWS * 64 * 2;
  float* stats = (float*)(ws + off); off += 256 * 4;
  float* sqmax = (float*)(ws + off); off += 64;
  double* part = (double*)(ws + off); off += 256 * 8;

  const int T64 = NROWS * 64;
  const int T3  = NROWS * 3;

  // ---- layer 1 (F=3 -> 64), VALU kNN ----
  sqnorm_kernel<<<NROWS / 256, 256, 0, stream>>>(x, sq, 3);
  knn_tiled<3><<<NROWS / 32, 256, 0, stream>>>(x, sq, idxb);
  mlp_pc_kernel<<<T64 / 256, 256, 0, stream>>>(x, W1, b1, P, CA, 3, 64, T64);
  aggregate_kernel<<<T64 / 256, 256, 0, stream>>>(idxb, P, CA, 64, T64);
  bn_stats_kernel<<<64, 256, 0, stream>>>(CA, stats);
  bn_apply_kernel<<<T64 / 256, 256, 0, stream>>>(CA, stats, g1, be1, CA, T64);

  // ---- layer 2 (F=64 -> 64), MFMA kNN ----
  sqnorm_kernel<<<NROWS / 256, 256, 0, stream>>>(CA, sq, 64);
  split_kernel<<<T64 / 256, 256, 0, stream>>>(CA, hib, lob, T64);
  batchmax_kernel<<<NB, 256, 0, stream>>>(sq, sqmax);
  knn_mfma<<<NB * 256, 256, 0, stream>>>(hib, lob, CA, sq, sqmax, idxb);
  mlp_pc_kernel<<<T64 / 256, 256, 0, stream>>>(CA, W2, b2, P, CB, 64, 64, T64);
  aggregate_kernel<<<T64 / 256, 256, 0, stream>>>(idxb, P, CB, 64, T64);
  bn_stats_kernel<<<64, 256, 0, stream>>>(CB, stats);
  bn_apply_kernel<<<T64 / 256, 256, 0, stream>>>(CB, stats, g2, be2, CB, T64);

  // ---- layer 3 (F=64 -> 3), MFMA kNN ----
  sqnorm_kernel<<<NROWS / 256, 256, 0, stream>>>(CB, sq, 64);
  split_kernel<<<T64 / 256, 256, 0, stream>>>(CB, hib, lob, T64);
  batchmax_kernel<<<NB, 256, 0, stream>>>(sq, sqmax);
  knn_mfma<<<NB * 256, 256, 0, stream>>>(hib, lob, CB, sq, sqmax, idxb);
  mlp_pc_kernel<<<T3 / 256, 256, 0, stream>>>(CB, W3, b3, P, CA, 64, 3, T3);
  aggregate_kernel<<<T3 / 256, 256, 0, stream>>>(idxb, P, CA, 3, T3);

  // ---- output + loss ----
  final_kernel<<<256, 256, 0, stream>>>(CA, tgt, out, part);
  loss_kernel<<<1, 256, 0, stream>>>(part, out);
}